// Round 12
// baseline (88.354 us; speedup 1.0000x reference)
//
#include <hip/hip_runtime.h>
#include <math.h>

#define NN 512
#define MM (NN * NN)
#define HW (NN * NN)
#define CH 3

__device__ __forceinline__ float dct_s(int k) {
    return (k == 0) ? 0.04419417382415922f : 0.0625f;
}

// ---------------- Stage A: T[h][wp] ---------------- (unchanged, ~8us)
__global__ void __launch_bounds__(256) k_stageA(
    const float* __restrict__ att, const float* __restrict__ rw,
    const float* __restrict__ cw, float* __restrict__ Tr, float* __restrict__ Tc)
{
    __shared__ float sD[2048];
    __shared__ float sRw[512];
    __shared__ float sAcc[256 * 9];
    const int tid = threadIdx.x;
    const int bx  = blockIdx.x;
    const int h0  = (bx >> 3) * 4;
    const int wp0 = (bx & 7) * 64;
    const int kc  = tid >> 6;
    const int wl  = tid & 63;
    const int wp  = wp0 + wl;
    const int hp0 = kc * 128;

    #pragma unroll
    for (int e = 0; e < 8; ++e) {
        int idx = tid * 8 + e;
        int hp = idx >> 2, i = idx & 3;
        int m = ((2 * (h0 + i) + 1) * hp) & 2047;
        sD[idx] = dct_s(hp) * cospif((float)m * (1.0f / 1024.0f));
    }
    sRw[tid] = rw[tid];
    sRw[256 + tid] = rw[256 + tid];
    __syncthreads();

    float ar0=0.f,ar1=0.f,ar2=0.f,ar3=0.f, as0=0.f,as1=0.f,as2=0.f,as3=0.f;
    #pragma unroll 4
    for (int t = 0; t < 128; ++t) {
        int hp = hp0 + t;
        float a = att[hp * NN + wp];
        float r = sRw[hp];
        float4 d = *reinterpret_cast<const float4*>(&sD[hp * 4]);
        float ra = r * a;
        ar0 += d.x * ra; as0 += d.x * a;
        ar1 += d.y * ra; as1 += d.y * a;
        ar2 += d.z * ra; as2 += d.z * a;
        ar3 += d.w * ra; as3 += d.w * a;
    }
    float* sa = &sAcc[tid * 9];
    sa[0]=ar0; sa[1]=ar1; sa[2]=ar2; sa[3]=ar3;
    sa[4]=as0; sa[5]=as1; sa[6]=as2; sa[7]=as3;
    __syncthreads();
    if (tid < 64) {
        float v[8];
        #pragma unroll
        for (int j = 0; j < 8; ++j)
            v[j] = sAcc[(0*64 + tid)*9 + j] + sAcc[(1*64 + tid)*9 + j]
                 + sAcc[(2*64 + tid)*9 + j] + sAcc[(3*64 + tid)*9 + j];
        float c = cw[wp0 + tid];
        #pragma unroll
        for (int i = 0; i < 4; ++i) {
            Tr[(h0 + i) * NN + wp0 + tid] = v[i];
            Tc[(h0 + i) * NN + wp0 + tid] = v[4 + i] * c;
        }
    }
}

// ---------------- Stage B: G[h][w] ---------------- (unchanged, ~8us)
__global__ void __launch_bounds__(256) k_stageB(
    const float* __restrict__ Tr, const float* __restrict__ Tc,
    float* __restrict__ Gr, float* __restrict__ Gc)
{
    __shared__ float sT[512 * 8];
    __shared__ float sAcc[256 * 9];
    const int tid = threadIdx.x;
    const int bx  = blockIdx.x;
    const int h0  = (bx >> 3) * 4;
    const int w0  = (bx & 7) * 64;
    const int kc  = tid >> 6;
    const int wl  = tid & 63;
    const int w   = w0 + wl;
    const int wp0 = kc * 128;

    #pragma unroll
    for (int i = 0; i < 4; ++i) {
        sT[tid * 8 + i]             = Tr[(h0 + i) * NN + tid];
        sT[tid * 8 + 4 + i]         = Tc[(h0 + i) * NN + tid];
        sT[(tid + 256) * 8 + i]     = Tr[(h0 + i) * NN + tid + 256];
        sT[(tid + 256) * 8 + 4 + i] = Tc[(h0 + i) * NN + tid + 256];
    }
    __syncthreads();

    float gr0=0.f,gr1=0.f,gr2=0.f,gr3=0.f, gc0=0.f,gc1=0.f,gc2=0.f,gc3=0.f;
    const int w2 = 2 * w + 1;
    int m = (w2 * wp0) & 2047;
    #pragma unroll 4
    for (int t = 0; t < 128; ++t) {
        int wp = wp0 + t;
        float s = (wp == 0) ? 0.04419417382415922f : 0.0625f;
        float d = s * cospif((float)m * (1.0f / 1024.0f));
        m = (m + w2) & 2047;
        float4 ta = *reinterpret_cast<const float4*>(&sT[wp * 8]);
        float4 tb = *reinterpret_cast<const float4*>(&sT[wp * 8 + 4]);
        gr0 += ta.x * d; gr1 += ta.y * d; gr2 += ta.z * d; gr3 += ta.w * d;
        gc0 += tb.x * d; gc1 += tb.y * d; gc2 += tb.z * d; gc3 += tb.w * d;
    }
    float* sa = &sAcc[tid * 9];
    sa[0]=gr0; sa[1]=gr1; sa[2]=gr2; sa[3]=gr3;
    sa[4]=gc0; sa[5]=gc1; sa[6]=gc2; sa[7]=gc3;
    __syncthreads();
    if (tid < 64) {
        float v[8];
        #pragma unroll
        for (int j = 0; j < 8; ++j)
            v[j] = sAcc[(0*64 + tid)*9 + j] + sAcc[(1*64 + tid)*9 + j]
                 + sAcc[(2*64 + tid)*9 + j] + sAcc[(3*64 + tid)*9 + j];
        #pragma unroll
        for (int i = 0; i < 4; ++i) {
            Gr[(h0 + i) * NN + w0 + tid] = v[i];
            Gc[(h0 + i) * NN + w0 + tid] = v[4 + i];
        }
    }
}

// ---------------- Reduce: G-in-registers, pure x-stream ----------------
// grid (64, 16): block = (4096-float hw-chunk, batch-quad). Each thread loads
// its 8 G float4s ONCE into 32 VGPRs, then streams 4b x 3c x 4 float4 of x --
// the hot loop's only VMEM traffic is x (201 MB total; G drops to 32 MB).
// All accumulators/addressing static (rule #20). No fences/atomics.
#define DOT(g, v) (g.x*v.x + g.y*v.y + g.z*v.z + g.w*v.w)
#define PLANE(AR, AC, XP) do {                                   \
    float4 v0 = *(const float4*)(XP);                            \
    float4 v1 = *(const float4*)((XP) + 1024);                   \
    float4 v2 = *(const float4*)((XP) + 2048);                   \
    float4 v3 = *(const float4*)((XP) + 3072);                   \
    AR += DOT(gr0, v0) + DOT(gr1, v1) + DOT(gr2, v2) + DOT(gr3, v3); \
    AC += DOT(gc0, v0) + DOT(gc1, v1) + DOT(gc2, v2) + DOT(gc3, v3); \
} while (0)

__global__ void __launch_bounds__(256) k_reduce(
    const float* __restrict__ x, const float* __restrict__ Gr,
    const float* __restrict__ Gc, float* __restrict__ partials)
{
    const int ck = blockIdx.x;            // 0..63 hw-chunk
    const int bg = blockIdx.y;            // 0..15 batch-quad
    const int t  = threadIdx.x;
    const int base = ck * 4096 + t * 4;

    float4 gr0 = *(const float4*)(Gr + base);
    float4 gr1 = *(const float4*)(Gr + base + 1024);
    float4 gr2 = *(const float4*)(Gr + base + 2048);
    float4 gr3 = *(const float4*)(Gr + base + 3072);
    float4 gc0 = *(const float4*)(Gc + base);
    float4 gc1 = *(const float4*)(Gc + base + 1024);
    float4 gc2 = *(const float4*)(Gc + base + 2048);
    float4 gc3 = *(const float4*)(Gc + base + 3072);

    const size_t b0 = (size_t)bg * 4;
    float ar0=0.f, ar1=0.f, ar2=0.f, ar3=0.f;
    float ac0=0.f, ac1=0.f, ac2=0.f, ac3=0.f;
    #pragma unroll
    for (int c = 0; c < 3; ++c) {
        const float* xp0 = x + ((b0 + 0) * 3 + c) * HW + base;
        const float* xp1 = x + ((b0 + 1) * 3 + c) * HW + base;
        const float* xp2 = x + ((b0 + 2) * 3 + c) * HW + base;
        const float* xp3 = x + ((b0 + 3) * 3 + c) * HW + base;
        PLANE(ar0, ac0, xp0);
        PLANE(ar1, ac1, xp1);
        PLANE(ar2, ac2, xp2);
        PLANE(ar3, ac3, xp3);
    }

    #pragma unroll
    for (int off = 32; off > 0; off >>= 1) {
        ar0 += __shfl_down(ar0, off);  ac0 += __shfl_down(ac0, off);
        ar1 += __shfl_down(ar1, off);  ac1 += __shfl_down(ac1, off);
        ar2 += __shfl_down(ar2, off);  ac2 += __shfl_down(ac2, off);
        ar3 += __shfl_down(ar3, off);  ac3 += __shfl_down(ac3, off);
    }
    __shared__ float sm[4][8];
    int wid = t >> 6;
    if ((t & 63) == 0) {
        sm[wid][0] = ar0; sm[wid][1] = ac0; sm[wid][2] = ar1; sm[wid][3] = ac1;
        sm[wid][4] = ar2; sm[wid][5] = ac2; sm[wid][6] = ar3; sm[wid][7] = ac3;
    }
    __syncthreads();
    if (t < 4) {   // t = batch index within quad
        float r = sm[0][t*2]   + sm[1][t*2]   + sm[2][t*2]   + sm[3][t*2];
        float c = sm[0][t*2+1] + sm[1][t*2+1] + sm[2][t*2+1] + sm[3][t*2+1];
        int b = bg * 4 + t;
        partials[(b * 64 + ck) * 2 + 0] = r;
        partials[(b * 64 + ck) * 2 + 1] = c;
    }
}

// 64 threads: b = tid. Sum 64 chunk-partials, fixed order.
__global__ void k_final(const float* __restrict__ partials, float* __restrict__ out) {
    int b = threadIdx.x;
    float r = 0.f, c = 0.f;
    #pragma unroll
    for (int i = 0; i < 64; ++i) {
        r += partials[(b * 64 + i) * 2 + 0];
        c += partials[(b * 64 + i) * 2 + 1];
    }
    const float inv = 1.0f / (float)(CH * HW);
    r *= inv; c *= inv;
    out[b * 2 + 0] = 1.0f / (1.0f + expf(-c));   // col_out first (stack order)
    out[b * 2 + 1] = 1.0f / (1.0f + expf(-r));
}

extern "C" void kernel_launch(void* const* d_in, const int* in_sizes, int n_in,
                              void* d_out, int out_size, void* d_ws, size_t ws_size,
                              hipStream_t stream) {
    const float* x   = (const float*)d_in[0];   // [64,3,512,512]
    const float* att = (const float*)d_in[1];   // [512,512]
    const float* rw  = (const float*)d_in[2];   // [512]
    const float* cw  = (const float*)d_in[3];   // [512]
    float* out = (float*)d_out;                 // [64,2]

    float* ws = (float*)d_ws;
    float* Tr = ws;
    float* Tc = ws + 1 * MM;
    float* Gr = ws + 2 * MM;
    float* Gc = ws + 3 * MM;
    float* partials = ws + 4 * MM;              // 64*64*2 = 8192 floats

    k_stageA<<<1024, 256, 0, stream>>>(att, rw, cw, Tr, Tc);
    k_stageB<<<1024, 256, 0, stream>>>(Tr, Tc, Gr, Gc);
    dim3 g(64, 16);
    k_reduce<<<g, 256, 0, stream>>>(x, Gr, Gc, partials);
    k_final<<<1, 64, 0, stream>>>(partials, out);
}